// Round 8
// baseline (238.198 us; speedup 1.0000x reference)
//
#include <hip/hip_runtime.h>
#include <hip/hip_bf16.h>
#include <stdint.h>

// GPTQ int4 linear via bf16 MFMA. M=32, K=8192, N=8192, group=64.
// R8: forking experiment. Main kernel = byte-identical R6 (best known, 209.9).
// Added pw_stream_probe between prep and main: pure linear read of all 128 MB
// of pw (2048 blocks, 16-deep dwordx4 grid-stride) -> warms Infinity Cache.
// Outcome decides R9: bench ~200 => LLC-prefetch works (win, pipeline it);
// ~235 => binder is intra-kernel; ~260+ => read-BW anomaly.

#define KK 8192
#define NN 8192
#define KP 4096      // int32 per weight row
#define NG 128       // quant groups per row
#define BN 16        // n per block
#define KSW 64       // ksteps (32 k) per wave: 4 waves * 64 * 32 = 8192
#define NKS 256      // total ksteps
#define SCK 8        // ksteps per superchunk
#define NSC 8        // superchunks per wave
#define PWBUF 8192   // bytes per superchunk pw buffer (16 rows x 512 B)
#define KSPLIT 2     // fallback only

typedef __attribute__((ext_vector_type(8))) short short8;
typedef __attribute__((ext_vector_type(4))) float floatx4;
typedef __attribute__((ext_vector_type(4))) int int4v;
typedef const __attribute__((address_space(1))) void* gbl_t;
typedef __attribute__((address_space(3))) void* lds_t;

__device__ __forceinline__ void async16(const void* g, void* l) {
    __builtin_amdgcn_global_load_lds((gbl_t)(uintptr_t)g, (lds_t)(uintptr_t)l, 16, 0, 0);
}

__device__ __forceinline__ unsigned pack_bf16x2(float lo, float hi) {
    union { __hip_bfloat162 h; unsigned u; } c;
    c.h = __float22bfloat162_rn(make_float2(lo, hi));
    return c.u;
}

// dequant 2 nibbles -> packed bf16x2 (RNE; w finite, no NaN path)
__device__ __forceinline__ unsigned dq2(int q, float sc, float zs) {
    float lo = fmaf((float)(q & 15),        sc, zs);
    float hi = fmaf((float)((q >> 4) & 15), sc, zs);
    unsigned ua = __float_as_uint(lo); ua += 0x7fffu + ((ua >> 16) & 1u);
    unsigned ub = __float_as_uint(hi); ub += 0x7fffu + ((ub >> 16) & 1u);
    return __builtin_amdgcn_perm(ub, ua, 0x07060302);   // [ub.hi16 : ua.hi16]
}

// --- R8 probe: stream all of pw (128 MB) linearly into the LLC. ---
// 2048 blocks x 256 thr, 16 iters of perfectly-coalesced dwordx4 per thread.
// XOR-reduce + impossible predicated store prevents DCE; no real side effects.
__global__ __launch_bounds__(256)
void pw_stream_probe(const int4v* __restrict__ pw4, unsigned* __restrict__ sink)
{
    const size_t base = (size_t)blockIdx.x * 256 + threadIdx.x;   // stride 524288
    unsigned acc = 0;
#pragma unroll
    for (int i = 0; i < 16; ++i) {
        const int4v v = pw4[base + (size_t)i * 524288];
        acc ^= (unsigned)v.x ^ (unsigned)v.y ^ (unsigned)v.z ^ (unsigned)v.w;
    }
    if (acc == 0x9E3779B9u) sink[blockIdx.x] = acc;   // effectively never taken
}

// blocks [0,xconv_blocks): x fp32 -> bf16 A-frags in xb; rest: out = bias.
__global__ void prep_kernel(const float* __restrict__ x, const float* __restrict__ bias,
                            ushort* __restrict__ xb, float* __restrict__ out,
                            int xconv_blocks)
{
    const int bx = blockIdx.x;
    if (bx < xconv_blocks) {
        const int tid = bx * 256 + threadIdx.x;   // 0..32767
        const int l   = tid & 63;
        const int ks  = (tid >> 6) & 255;
        const int mt  = tid >> 14;
        const int m   = (l & 15) + 16 * mt;
        const int kb  = ks * 32 + (l >> 4) * 8;
        const float* src = x + (size_t)m * KK + kb;
        const float4 a = *(const float4*)(src);
        const float4 b = *(const float4*)(src + 4);
        *(uint4*)(xb + (size_t)tid * 8) =
            make_uint4(pack_bf16x2(a.x, a.y), pack_bf16x2(a.z, a.w),
                       pack_bf16x2(b.x, b.y), pack_bf16x2(b.z, b.w));
    } else {
        const int f4 = (bx - xconv_blocks) * 256 + threadIdx.x;  // 0..65535
        const int n4 = f4 & (NN / 4 - 1);
        ((float4*)out)[f4] = ((const float4*)bias)[n4];
    }
}

__global__ __launch_bounds__(256, 2)
void gptq_mfma_main(const int*   __restrict__ pw,
                    const float* __restrict__ scales,
                    const float* __restrict__ zeros,
                    const float* __restrict__ bias,
                    const ushort* __restrict__ xb,
                    float* __restrict__ out)
{
    __shared__ uint4 smem4[65536 / 16];    // 4 waves x 2 x 8 KB pw buffers
    uint8_t* smem = (uint8_t*)smem4;

    const int tid  = threadIdx.x;
    const int lane = tid & 63;
    const int wave = tid >> 6;
    const int n0   = blockIdx.x * BN;
    const int nl   = lane & 15;     // B-frag col (n_local)
    const int kq   = lane >> 4;     // k-quad
    const int ks0  = wave * KSW;    // this wave's first kstep

    // ---- scales/zeros -> registers: 32 groups per wave ----
    float scr[32], zsr[32];
    {
        const float* sp = scales + (size_t)(n0 + nl) * NG + wave * 32;
        const float* zp = zeros  + (size_t)(n0 + nl) * NG + wave * 32;
#pragma unroll
        for (int i = 0; i < 8; ++i) {
            const float4 s4 = *(const float4*)(sp + i * 4);
            const float4 z4 = *(const float4*)(zp + i * 4);
            scr[i*4+0] = s4.x; zsr[i*4+0] = -z4.x * s4.x;
            scr[i*4+1] = s4.y; zsr[i*4+1] = -z4.y * s4.y;
            scr[i*4+2] = s4.z; zsr[i*4+2] = -z4.z * s4.z;
            scr[i*4+3] = s4.w; zsr[i*4+3] = -z4.w * s4.w;
        }
    }

    // ---- staging constants: instr i covers rows 2i,2i+1; 512 B contiguous/row ----
    const int hw = lane >> 5, h = lane & 31, js = h >> 2, q = h & 3;
    int bofs[8];
#pragma unroll
    for (int i = 0; i < 8; ++i) {
        const int r  = 2 * i + hw;
        const int jg = js ^ (r & 7);
        const int qg = q ^ (i & 3);
        bofs[i] = (n0 + r) * KP + jg * 16 + qg * 4;   // int32 units, + kb*16 later
    }
    uint8_t* wbuf = smem + wave * (2 * PWBUF);
    const int pwo = (nl >> 1) * 1024 + (nl & 1) * 512 + ((kq ^ ((nl >> 1) & 3)) * 16);
    const int jx  = nl & 7;

#define STAGE(s) do {                                                  \
        uint8_t* b_ = wbuf + ((s) & 1) * PWBUF;                        \
        const int kb16_ = (ks0 + (s) * SCK) * 16;                      \
        _Pragma("unroll")                                              \
        for (int i_ = 0; i_ < 8; ++i_)                                 \
            async16(pw + bofs[i_] + kb16_, b_ + i_ * 1024);            \
    } while (0)

    const uint4* xfp = (const uint4*)xb;
    floatx4 acc0 = {0.f, 0.f, 0.f, 0.f};
    floatx4 acc1 = {0.f, 0.f, 0.f, 0.f};

    STAGE(0);

#pragma unroll
    for (int s = 0; s < NSC; ++s) {
        if (s + 1 < NSC) {
            STAGE(s + 1);
            asm volatile("s_waitcnt vmcnt(8)" ::: "memory");
        } else {
            asm volatile("s_waitcnt vmcnt(0)" ::: "memory");
        }
        uint8_t* b = wbuf + (s & 1) * PWBUF;
#pragma unroll
        for (int j = 0; j < SCK; ++j) {
            const int ks = ks0 + s * SCK + j;
            const int4 p = *(const int4*)(b + pwo + ((j ^ jx) * 64));
            union { uint4 v; short8 sv; } a0, a1, bf;
            a0.v = xfp[(size_t)(0 * NKS + ks) * 64 + lane];
            a1.v = xfp[(size_t)(1 * NKS + ks) * 64 + lane];
            const float sc = scr[s * 4 + (j >> 1)];
            const float zs = zsr[s * 4 + (j >> 1)];
            bf.v.x = dq2(p.x, sc, zs);
            bf.v.y = dq2(p.y, sc, zs);
            bf.v.z = dq2(p.z, sc, zs);
            bf.v.w = dq2(p.w, sc, zs);
            acc0 = __builtin_amdgcn_mfma_f32_16x16x32_bf16(a0.sv, bf.sv, acc0, 0, 0, 0);
            acc1 = __builtin_amdgcn_mfma_f32_16x16x32_bf16(a1.sv, bf.sv, acc1, 0, 0, 0);
        }
    }
#undef STAGE

    // ---- epilogue: cross-wave reduce via LDS overlay, direct store + bias ----
    __syncthreads();
    float* red = (float*)smem;   // 8 KB overlay
#pragma unroll
    for (int r = 0; r < 4; ++r) {
        const int row = kq * 4 + r;
        red[(wave * 2 + 0) * 256 + row * 16 + nl] = acc0[r];
        red[(wave * 2 + 1) * 256 + row * 16 + nl] = acc1[r];
    }
    __syncthreads();

#pragma unroll
    for (int i = 0; i < 2; ++i) {
        const int e   = i * 256 + tid;
        const int mt  = e >> 8;
        const int idx = e & 255;
        const float sv = red[(0 * 2 + mt) * 256 + idx] + red[(1 * 2 + mt) * 256 + idx]
                       + red[(2 * 2 + mt) * 256 + idx] + red[(3 * 2 + mt) * 256 + idx];
        const int n = n0 + (idx & 15);
        out[(size_t)(mt * 16 + (idx >> 4)) * NN + n] = sv + bias[n];
    }
}

// Fallback (no workspace): register-path kernel, direct fp32 x loads, atomics.
__global__ __launch_bounds__(256, 4)
void gptq_mfma_fallback(const int*   __restrict__ pw,
                        const float* __restrict__ scales,
                        const float* __restrict__ zeros,
                        const float* __restrict__ x,
                        float* __restrict__ out)
{
    __shared__ float s_lds[64][BN + 1];
    __shared__ float z_lds[64][BN + 1];
    __shared__ float red[4][2][256];

    const int tid  = threadIdx.x;
    const int lane = tid & 63;
    const int wave = tid >> 6;
    const int kh   = blockIdx.x & (KSPLIT - 1);
    const int n0   = (blockIdx.x >> 1) * BN;
    const int g0   = kh * 64;

    {
        const int r  = tid >> 4;
        const int gb = (tid & 15) * 4;
        const float4 s4 = *(const float4*)(scales + (size_t)(n0 + r) * NG + g0 + gb);
        const float4 z4 = *(const float4*)(zeros  + (size_t)(n0 + r) * NG + g0 + gb);
        s_lds[gb + 0][r] = s4.x; s_lds[gb + 1][r] = s4.y;
        s_lds[gb + 2][r] = s4.z; s_lds[gb + 3][r] = s4.w;
        z_lds[gb + 0][r] = z4.x; z_lds[gb + 1][r] = z4.y;
        z_lds[gb + 2][r] = z4.z; z_lds[gb + 3][r] = z4.w;
    }
    __syncthreads();

    const int nl = lane & 15;
    const int kq = lane >> 4;
    const int* pwp = pw + (size_t)(n0 + nl) * KP + kq * 4;
    const int ks0 = kh * 128 + wave * 32;

    auto load_xfrag = [&](int mt, int ks) -> uint4 {
        const float* src = x + (size_t)(nl + 16 * mt) * KK + ks * 32 + kq * 8;
        const float4 a = *(const float4*)(src);
        const float4 b = *(const float4*)(src + 4);
        return make_uint4(pack_bf16x2(a.x, a.y), pack_bf16x2(a.z, a.w),
                          pack_bf16x2(b.x, b.y), pack_bf16x2(b.z, b.w));
    };

    floatx4 acc0 = {0.f, 0.f, 0.f, 0.f};
    floatx4 acc1 = {0.f, 0.f, 0.f, 0.f};
    int4v pwb[4];
    uint4 x0b[4], x1b[4];

#pragma unroll
    for (int i = 0; i < 3; ++i) {
        const int ks = ks0 + i;
        pwb[i] = *(const int4v*)(pwp + ks * 16);
        x0b[i] = load_xfrag(0, ks);
        x1b[i] = load_xfrag(1, ks);
    }

#pragma unroll 4
    for (int i = 0; i < 32; ++i) {
        const int slot = i & 3;
        if (i + 3 < 32) {
            const int ks = ks0 + i + 3;
            const int ps = (i + 3) & 3;
            pwb[ps] = *(const int4v*)(pwp + ks * 16);
            x0b[ps] = load_xfrag(0, ks);
            x1b[ps] = load_xfrag(1, ks);
        }
        const int gl  = (wave * 32 + i) >> 1;
        const float sc = s_lds[gl][nl];
        const float zs = -z_lds[gl][nl] * sc;

        union { uint4 v; short8 sv; } bf, a0, a1;
        const int4v p = pwb[slot];
        bf.v.x = dq2(p.x, sc, zs);
        bf.v.y = dq2(p.y, sc, zs);
        bf.v.z = dq2(p.z, sc, zs);
        bf.v.w = dq2(p.w, sc, zs);
        a0.v = x0b[slot];
        a1.v = x1b[slot];
        acc0 = __builtin_amdgcn_mfma_f32_16x16x32_bf16(a0.sv, bf.sv, acc0, 0, 0, 0);
        acc1 = __builtin_amdgcn_mfma_f32_16x16x32_bf16(a1.sv, bf.sv, acc1, 0, 0, 0);
    }

#pragma unroll
    for (int r = 0; r < 4; ++r) {
        const int row = kq * 4 + r;
        red[wave][0][row * 16 + nl] = acc0[r];
        red[wave][1][row * 16 + nl] = acc1[r];
    }
    __syncthreads();

#pragma unroll
    for (int i = 0; i < 2; ++i) {
        const int e   = i * 256 + tid;
        const int mt  = e >> 8;
        const int idx = e & 255;
        const float s = red[0][mt][idx] + red[1][mt][idx] + red[2][mt][idx] + red[3][mt][idx];
        atomicAdd(out + (size_t)(mt * 16 + (idx >> 4)) * NN + n0 + (idx & 15), s);
    }
}

extern "C" void kernel_launch(void* const* d_in, const int* in_sizes, int n_in,
                              void* d_out, int out_size, void* d_ws, size_t ws_size,
                              hipStream_t stream) {
    const float* x      = (const float*)d_in[0];
    const int*   pw     = (const int*)  d_in[1];
    const float* scales = (const float*)d_in[2];
    const float* zeros  = (const float*)d_in[3];
    const float* bias   = (const float*)d_in[4];
    float* out = (float*)d_out;

    const size_t need = (size_t)32768 * 16 + (size_t)(1 << 20);   // xb + probe sink
    if (d_ws != nullptr && ws_size >= need) {
        ushort* xb = (ushort*)d_ws;
        unsigned* sink = (unsigned*)((uint8_t*)d_ws + (1 << 20));
        prep_kernel<<<128, 256, 0, stream>>>(x, bias, xb, out, 128);   // xconv only
        pw_stream_probe<<<2048, 256, 0, stream>>>((const int4v*)pw, sink);
        gptq_mfma_main<<<NN / BN, 256, 0, stream>>>(pw, scales, zeros, bias, xb, out);
    } else {
        prep_kernel<<<256, 256, 0, stream>>>(x, bias, nullptr, out, 0); // bias fill
        gptq_mfma_fallback<<<512 * KSPLIT, 256, 0, stream>>>(pw, scales, zeros, x, out);
    }
}

// Round 9
// 208.871 us; speedup vs baseline: 1.1404x; 1.1404x over previous
//
#include <hip/hip_runtime.h>
#include <hip/hip_bf16.h>
#include <stdint.h>

// GPTQ int4 linear via bf16 MFMA. M=32, K=8192, N=8192, group=64.
// R9: cut vmem bytes. R8 probe proved pure pw read = 28 us (4.5 TB/s) and
// L3-warmth doesn't help -> binder is total bytes through the per-CU vmem
// path: pw 128 MB + xb re-reads 256 MB (each of 512 blocks re-read all xb).
// Fix: BN=64 (4 B-frags amortize each A-frag), KSPLIT=4 (grid stays 512):
// xb traffic 256->64 MB. Scales/zeros in padded LDS; 4-deep register
// pipeline; LDS reduce + atomicAdd onto bias-prefilled out.

#define KK 8192
#define NN 8192
#define KP 4096      // int32 per weight row
#define NG 128       // quant groups per row
#define BN 64        // n per block
#define KSPLIT 4
#define KSPW 16      // ksteps (32 k each) per wave
#define NKS 256      // total ksteps

typedef __attribute__((ext_vector_type(8))) short short8;
typedef __attribute__((ext_vector_type(4))) float floatx4;
typedef __attribute__((ext_vector_type(4))) int int4v;

__device__ __forceinline__ unsigned pack_bf16x2(float lo, float hi) {
    union { __hip_bfloat162 h; unsigned u; } c;
    c.h = __float22bfloat162_rn(make_float2(lo, hi));
    return c.u;
}

// dequant 2 nibbles -> packed bf16x2 (RNE; w finite, no NaN path)
__device__ __forceinline__ unsigned dq2(int q, float sc, float zs) {
    float lo = fmaf((float)(q & 15),        sc, zs);
    float hi = fmaf((float)((q >> 4) & 15), sc, zs);
    unsigned ua = __float_as_uint(lo); ua += 0x7fffu + ((ua >> 16) & 1u);
    unsigned ub = __float_as_uint(hi); ub += 0x7fffu + ((ub >> 16) & 1u);
    return __builtin_amdgcn_perm(ub, ua, 0x07060302);   // [ub.hi16 : ua.hi16]
}

// blocks [0,xconv_blocks): x fp32 -> bf16 A-frags in xb; rest: out = bias.
__global__ void prep_kernel(const float* __restrict__ x, const float* __restrict__ bias,
                            ushort* __restrict__ xb, float* __restrict__ out,
                            int xconv_blocks)
{
    const int bx = blockIdx.x;
    if (bx < xconv_blocks) {
        const int tid = bx * 256 + threadIdx.x;   // 0..32767
        const int l   = tid & 63;
        const int ks  = (tid >> 6) & 255;
        const int mt  = tid >> 14;
        const int m   = (l & 15) + 16 * mt;
        const int kb  = ks * 32 + (l >> 4) * 8;
        const float* src = x + (size_t)m * KK + kb;
        const float4 a = *(const float4*)(src);
        const float4 b = *(const float4*)(src + 4);
        *(uint4*)(xb + (size_t)tid * 8) =
            make_uint4(pack_bf16x2(a.x, a.y), pack_bf16x2(a.z, a.w),
                       pack_bf16x2(b.x, b.y), pack_bf16x2(b.z, b.w));
    } else {
        const int f4 = (bx - xconv_blocks) * 256 + threadIdx.x;  // 0..65535
        const int n4 = f4 & (NN / 4 - 1);
        ((float4*)out)[f4] = ((const float4*)bias)[n4];
    }
}

__global__ __launch_bounds__(256, 2)
void gptq_mfma_main(const int*   __restrict__ pw,
                    const float* __restrict__ scales,
                    const float* __restrict__ zeros,
                    const ushort* __restrict__ xb,
                    float* __restrict__ out)
{
    __shared__ float sc_lds[32][65];      // [group_local][n_local], pad 65
    __shared__ float zs_lds[32][65];      // zs = -z*s
    __shared__ float red[4][32][68];      // [wave][m][n_local], pad 68

    const int tid  = threadIdx.x;
    const int lane = tid & 63;
    const int wave = tid >> 6;
    const int kh   = blockIdx.x & (KSPLIT - 1);
    const int n0   = (blockIdx.x >> 2) * BN;
    const int nl   = lane & 15;     // B-frag col within 16-n frag
    const int kq   = lane >> 4;     // k-quad
    const int ks0  = kh * 64 + wave * KSPW;   // global kstep base for this wave

    // ---- stage scales/zeros for 64 rows x 32 groups; zs = -z*s ----
    {
        const int r  = tid >> 2;          // n_local 0..63
        const int go = (tid & 3) * 8;     // group_local base
        const float* sp = scales + (size_t)(n0 + r) * NG + kh * 32 + go;
        const float* zp = zeros  + (size_t)(n0 + r) * NG + kh * 32 + go;
#pragma unroll
        for (int t = 0; t < 2; ++t) {
            const float4 s4 = *(const float4*)(sp + t * 4);
            const float4 z4 = *(const float4*)(zp + t * 4);
            sc_lds[go + t*4 + 0][r] = s4.x; zs_lds[go + t*4 + 0][r] = -z4.x * s4.x;
            sc_lds[go + t*4 + 1][r] = s4.y; zs_lds[go + t*4 + 1][r] = -z4.y * s4.y;
            sc_lds[go + t*4 + 2][r] = s4.z; zs_lds[go + t*4 + 2][r] = -z4.z * s4.z;
            sc_lds[go + t*4 + 3][r] = s4.w; zs_lds[go + t*4 + 3][r] = -z4.w * s4.w;
        }
    }
    __syncthreads();

    // ---- pw pointers: 4 weight-row streams per lane (rows nl + 16f) ----
    const int* pwp[4];
#pragma unroll
    for (int f = 0; f < 4; ++f)
        pwp[f] = pw + (size_t)(n0 + f * 16 + nl) * KP + kq * 4;
    const uint4* xfp = (const uint4*)xb;

    floatx4 acc[4][2];
#pragma unroll
    for (int f = 0; f < 4; ++f)
#pragma unroll
        for (int mt = 0; mt < 2; ++mt)
            acc[f][mt] = (floatx4){0.f, 0.f, 0.f, 0.f};

    int4v pb[4][4];    // [slot][frag]
    uint4 xa[4][2];    // [slot][mt]

#pragma unroll
    for (int i = 0; i < 3; ++i) {
        const int ks = ks0 + i;
        xa[i][0] = xfp[(size_t)(0 * NKS + ks) * 64 + lane];
        xa[i][1] = xfp[(size_t)(1 * NKS + ks) * 64 + lane];
#pragma unroll
        for (int f = 0; f < 4; ++f)
            pb[i][f] = *(const int4v*)(pwp[f] + ks * 16);
    }

#pragma unroll
    for (int i = 0; i < KSPW; ++i) {
        const int slot = i & 3;
        if (i + 3 < KSPW) {
            const int ks = ks0 + i + 3;
            const int ps = (i + 3) & 3;
            xa[ps][0] = xfp[(size_t)(0 * NKS + ks) * 64 + lane];
            xa[ps][1] = xfp[(size_t)(1 * NKS + ks) * 64 + lane];
#pragma unroll
            for (int f = 0; f < 4; ++f)
                pb[ps][f] = *(const int4v*)(pwp[f] + ks * 16);
        }
        const int gl = (wave * KSPW + i) >> 1;   // group local to block

        union { uint4 v; short8 sv; } a0, a1;
        a0.v = xa[slot][0];
        a1.v = xa[slot][1];
#pragma unroll
        for (int f = 0; f < 4; ++f) {
            const float sc = sc_lds[gl][f * 16 + nl];
            const float zs = zs_lds[gl][f * 16 + nl];
            union { uint4 v; short8 sv; } bf;
            const int4v p = pb[slot][f];
            bf.v.x = dq2(p.x, sc, zs);
            bf.v.y = dq2(p.y, sc, zs);
            bf.v.z = dq2(p.z, sc, zs);
            bf.v.w = dq2(p.w, sc, zs);
            acc[f][0] = __builtin_amdgcn_mfma_f32_16x16x32_bf16(a0.sv, bf.sv, acc[f][0], 0, 0, 0);
            acc[f][1] = __builtin_amdgcn_mfma_f32_16x16x32_bf16(a1.sv, bf.sv, acc[f][1], 0, 0, 0);
        }
    }

    // ---- epilogue: 4-wave (K-split within block) LDS reduce, then atomicAdd ----
#pragma unroll
    for (int f = 0; f < 4; ++f)
#pragma unroll
        for (int mt = 0; mt < 2; ++mt)
#pragma unroll
            for (int r = 0; r < 4; ++r)
                red[wave][mt * 16 + kq * 4 + r][f * 16 + nl] = acc[f][mt][r];
    __syncthreads();

#pragma unroll
    for (int j = 0; j < 8; ++j) {
        const int e = j * 256 + tid;      // 0..2047 partial elems
        const int m = e >> 6, c = e & 63;
        const float s = red[0][m][c] + red[1][m][c] + red[2][m][c] + red[3][m][c];
        atomicAdd(out + (size_t)m * NN + n0 + c, s);
    }
}

// Fallback (no workspace): register-path kernel, direct fp32 x loads, atomics.
__global__ __launch_bounds__(256, 4)
void gptq_mfma_fallback(const int*   __restrict__ pw,
                        const float* __restrict__ scales,
                        const float* __restrict__ zeros,
                        const float* __restrict__ x,
                        float* __restrict__ out)
{
    __shared__ float s_lds[64][17];
    __shared__ float z_lds[64][17];
    __shared__ float red[4][2][256];

    const int tid  = threadIdx.x;
    const int lane = tid & 63;
    const int wave = tid >> 6;
    const int kh   = blockIdx.x & 1;
    const int n0   = (blockIdx.x >> 1) * 16;
    const int g0   = kh * 64;

    {
        const int r  = tid >> 4;
        const int gb = (tid & 15) * 4;
        const float4 s4 = *(const float4*)(scales + (size_t)(n0 + r) * NG + g0 + gb);
        const float4 z4 = *(const float4*)(zeros  + (size_t)(n0 + r) * NG + g0 + gb);
        s_lds[gb + 0][r] = s4.x; s_lds[gb + 1][r] = s4.y;
        s_lds[gb + 2][r] = s4.z; s_lds[gb + 3][r] = s4.w;
        z_lds[gb + 0][r] = z4.x; z_lds[gb + 1][r] = z4.y;
        z_lds[gb + 2][r] = z4.z; z_lds[gb + 3][r] = z4.w;
    }
    __syncthreads();

    const int nl = lane & 15;
    const int kq = lane >> 4;
    const int* pwp = pw + (size_t)(n0 + nl) * KP + kq * 4;
    const int ks0 = kh * 128 + wave * 32;

    auto load_xfrag = [&](int mt, int ks) -> uint4 {
        const float* src = x + (size_t)(nl + 16 * mt) * KK + ks * 32 + kq * 8;
        const float4 a = *(const float4*)(src);
        const float4 b = *(const float4*)(src + 4);
        return make_uint4(pack_bf16x2(a.x, a.y), pack_bf16x2(a.z, a.w),
                          pack_bf16x2(b.x, b.y), pack_bf16x2(b.z, b.w));
    };

    floatx4 acc0 = {0.f, 0.f, 0.f, 0.f};
    floatx4 acc1 = {0.f, 0.f, 0.f, 0.f};
    int4v pwb[4];
    uint4 x0b[4], x1b[4];

#pragma unroll
    for (int i = 0; i < 3; ++i) {
        const int ks = ks0 + i;
        pwb[i] = *(const int4v*)(pwp + ks * 16);
        x0b[i] = load_xfrag(0, ks);
        x1b[i] = load_xfrag(1, ks);
    }

#pragma unroll 4
    for (int i = 0; i < 32; ++i) {
        const int slot = i & 3;
        if (i + 3 < 32) {
            const int ks = ks0 + i + 3;
            const int ps = (i + 3) & 3;
            pwb[ps] = *(const int4v*)(pwp + ks * 16);
            x0b[ps] = load_xfrag(0, ks);
            x1b[ps] = load_xfrag(1, ks);
        }
        const int gl  = (wave * 32 + i) >> 1;
        const float sc = s_lds[gl][nl];
        const float zs = -z_lds[gl][nl] * sc;

        union { uint4 v; short8 sv; } bf, a0, a1;
        const int4v p = pwb[slot];
        bf.v.x = dq2(p.x, sc, zs);
        bf.v.y = dq2(p.y, sc, zs);
        bf.v.z = dq2(p.z, sc, zs);
        bf.v.w = dq2(p.w, sc, zs);
        a0.v = x0b[slot];
        a1.v = x1b[slot];
        acc0 = __builtin_amdgcn_mfma_f32_16x16x32_bf16(a0.sv, bf.sv, acc0, 0, 0, 0);
        acc1 = __builtin_amdgcn_mfma_f32_16x16x32_bf16(a1.sv, bf.sv, acc1, 0, 0, 0);
    }

#pragma unroll
    for (int r = 0; r < 4; ++r) {
        const int row = kq * 4 + r;
        red[wave][0][row * 16 + nl] = acc0[r];
        red[wave][1][row * 16 + nl] = acc1[r];
    }
    __syncthreads();

#pragma unroll
    for (int i = 0; i < 2; ++i) {
        const int e   = i * 256 + tid;
        const int mt  = e >> 8;
        const int idx = e & 255;
        const float s = red[0][mt][idx] + red[1][mt][idx] + red[2][mt][idx] + red[3][mt][idx];
        atomicAdd(out + (size_t)(mt * 16 + (idx >> 4)) * NN + n0 + (idx & 15), s);
    }
}

extern "C" void kernel_launch(void* const* d_in, const int* in_sizes, int n_in,
                              void* d_out, int out_size, void* d_ws, size_t ws_size,
                              hipStream_t stream) {
    const float* x      = (const float*)d_in[0];
    const int*   pw     = (const int*)  d_in[1];
    const float* scales = (const float*)d_in[2];
    const float* zeros  = (const float*)d_in[3];
    const float* bias   = (const float*)d_in[4];
    float* out = (float*)d_out;

    const size_t need = (size_t)32768 * 16;   // 512 KB of bf16 A-frags
    if (d_ws != nullptr && ws_size >= need) {
        ushort* xb = (ushort*)d_ws;
        prep_kernel<<<128 + 256, 256, 0, stream>>>(x, bias, xb, out, 128);
        gptq_mfma_main<<<(NN / BN) * KSPLIT, 256, 0, stream>>>(pw, scales, zeros, xb, out);
    } else {
        prep_kernel<<<256, 256, 0, stream>>>(x, bias, nullptr, out, 0);
        gptq_mfma_fallback<<<1024, 256, 0, stream>>>(pw, scales, zeros, x, out);
    }
}